// Round 1
// baseline (557.052 us; speedup 1.0000x reference)
//
#include <hip/hip_runtime.h>
#include <math.h>

typedef float f32x4 __attribute__((ext_vector_type(4)));

// ---------------------------------------------------------------------------
// R12: split compute from the broadcast store stream.
//
// k_mlp: sinusoidal embed + Linear/SiLU x2 (identical math/order to R11 ->
//        bitwise-same h2), but writes ONLY h2[b,:] into row 0 of each output
//        image (4 KB/block). 72 KB LDS, 1024 blocks x 256 threads.
//
// k_bcast: zero-LDS pure store stream. One block per image: read row 0
//        (512 B, L2/L3-hit; visible via kernel-boundary flush), broadcast to
//        rows 1..127. Row 0 already correct -> skipped -> no write race.
//        This kernel is memset-shaped and should run at fill BW (~6.3 TB/s).
//
// Rationale: fused R11 kernel ran ~199 us = 2.7 TB/s effective because the
// per-block {stage 2x64KB W, embed, 2 GEMVs, 4 syncthreads} phase serialized
// against the store stream at 2 blocks/CU. Store roofline is ~85 us.
// ---------------------------------------------------------------------------
__global__ __launch_bounds__(256) void k_mlp(
    const float* __restrict__ t,
    const float* __restrict__ W1, const float* __restrict__ b1,
    const float* __restrict__ W2, const float* __restrict__ b2,
    float* __restrict__ out)
{
    __shared__ __attribute__((aligned(16))) float4 WQ[4096];    // 64 KB
    __shared__ __attribute__((aligned(16))) float  EH[8 * 128]; // 4 KB: emb -> h2
    __shared__ __attribute__((aligned(16))) float  H1[8 * 128]; // 4 KB

    const int tid  = threadIdx.x;
    const int base = blockIdx.x * 8;

    const int r  = tid & 127;     // neuron
    const int g  = tid >> 7;      // wave-uniform: batches 4g..4g+3
    const int xr = r & 31;        // xor key

    // ---- stage W1 (coalesced read, swizzled conflict-free b128 write) ----
    {
        const float4* gp = (const float4*)W1;   // 4096 float4
        #pragma unroll
        for (int it = 0; it < 16; ++it) {
            int idx4 = it * 256 + tid;
            float4 q = gp[idx4];
            int rr = idx4 >> 5, c = idx4 & 31;
            WQ[rr * 32 + (c ^ (rr & 31))] = q;
        }
    }
    // ---- embedding: 8 batches x 64 freqs = 512 items, 2/thread ----
    #pragma unroll
    for (int i = 0; i < 2; ++i) {
        int idx = i * 256 + tid;
        int b = idx >> 6, k = idx & 63;
        double a   = (double)k * (6.907755278982137 / 63.0);
        float freq = (float)exp(a);
        float ang  = 6.2831853071795865f * freq;
        float ph   = t[base + b] * ang;
        float sv, cv;
        sincosf(ph, &sv, &cv);
        EH[b * 128 + k]      = sv;
        EH[b * 128 + 64 + k] = cv;
    }
    __syncthreads();

    // ---- layer 1: H1[b][r] = silu(b1[r] + sum_k emb[b][k]*W1[r,k]) ----
    {
        float acc[4];
        float bv = b1[r];
        #pragma unroll
        for (int m = 0; m < 4; ++m) acc[m] = bv;
        #pragma unroll
        for (int k4 = 0; k4 < 32; ++k4) {
            float4 w = WQ[r * 32 + (k4 ^ xr)];
            #pragma unroll
            for (int m = 0; m < 4; ++m) {
                float4 ev = ((const float4*)(EH + (g * 4 + m) * 128))[k4]; // broadcast
                acc[m] = fmaf(w.x, ev.x, acc[m]);
                acc[m] = fmaf(w.y, ev.y, acc[m]);
                acc[m] = fmaf(w.z, ev.z, acc[m]);
                acc[m] = fmaf(w.w, ev.w, acc[m]);
            }
        }
        #pragma unroll
        for (int m = 0; m < 4; ++m) {
            float a = acc[m];
            H1[(g * 4 + m) * 128 + r] = a / (1.0f + expf(-a));   // SiLU
        }
    }
    __syncthreads();   // fences H1 writes + layer-1 WQ reads

    // ---- restage W2 over WQ ----
    {
        const float4* gp = (const float4*)W2;
        #pragma unroll
        for (int it = 0; it < 16; ++it) {
            int idx4 = it * 256 + tid;
            float4 q = gp[idx4];
            int rr = idx4 >> 5, c = idx4 & 31;
            WQ[rr * 32 + (c ^ (rr & 31))] = q;
        }
    }
    __syncthreads();

    // ---- layer 2: EH[b][r] = silu(b2[r] + sum_k H1[b][k]*W2[r,k]) ----
    {
        float acc[4];
        float bv = b2[r];
        #pragma unroll
        for (int m = 0; m < 4; ++m) acc[m] = bv;
        #pragma unroll
        for (int k4 = 0; k4 < 32; ++k4) {
            float4 w = WQ[r * 32 + (k4 ^ xr)];
            #pragma unroll
            for (int m = 0; m < 4; ++m) {
                float4 ev = ((const float4*)(H1 + (g * 4 + m) * 128))[k4]; // broadcast
                acc[m] = fmaf(w.x, ev.x, acc[m]);
                acc[m] = fmaf(w.y, ev.y, acc[m]);
                acc[m] = fmaf(w.z, ev.z, acc[m]);
                acc[m] = fmaf(w.w, ev.w, acc[m]);
            }
        }
        #pragma unroll
        for (int m = 0; m < 4; ++m) {
            float a = acc[m];
            EH[(g * 4 + m) * 128 + r] = a / (1.0f + expf(-a));   // SiLU
        }
    }
    __syncthreads();

    // ---- store h2 -> row 0 of each image: 8 batches x 32 float4 = 256 f32x4,
    // one per thread, coalesced 512 B per batch.
    {
        int b  = tid >> 5;       // batch within block
        int j4 = tid & 31;       // float4 column
        f32x4 v = *(const f32x4*)&EH[b * 128 + j4 * 4];
        *(f32x4*)(out + (size_t)(base + b) * 16384 + j4 * 4) = v;
    }
}

// One block per image. Read row 0 (512 B), broadcast to rows 1..127.
// Image = 4096 float4; chunk c covers float4 [c*256, c*256+256) = rows
// [8c, 8c+8). Thread writes chunks c*256+tid; its column (tid&31) is
// invariant across chunks -> v loaded once. c==0/tid<32 is row 0: skip.
__global__ __launch_bounds__(256) void k_bcast(float* __restrict__ out)
{
    const int tid = threadIdx.x;
    f32x4* d = (f32x4*)(out + (size_t)blockIdx.x * 16384);
    f32x4 v = d[tid & 31];                 // row 0 of this image (written by k_mlp)
    if (tid >= 32) d[tid] = v;             // chunk 0, rows 1..7 (skip row 0)
    #pragma unroll
    for (int c = 1; c < 16; ++c) {
        d[c * 256 + tid] = v;              // rows 8c .. 8c+7
    }
}

extern "C" void kernel_launch(void* const* d_in, const int* in_sizes, int n_in,
                              void* d_out, int out_size, void* d_ws, size_t ws_size,
                              hipStream_t stream) {
    const float* t  = (const float*)d_in[0];
    const float* W1 = (const float*)d_in[1];
    const float* b1 = (const float*)d_in[2];
    const float* W2 = (const float*)d_in[3];
    const float* b2 = (const float*)d_in[4];
    float* out = (float*)d_out;
    const int B = in_sizes[0];   // 8192

    k_mlp<<<B / 8, 256, 0, stream>>>(t, W1, b1, W2, b2, out);
    k_bcast<<<B, 256, 0, stream>>>(out);
}

// Round 2
// 555.501 us; speedup vs baseline: 1.0028x; 1.0028x over previous
//
#include <hip/hip_runtime.h>
#include <math.h>

typedef float f32x4 __attribute__((ext_vector_type(4)));

// ---------------------------------------------------------------------------
// R13: single fused kernel, NO weight staging.
//
// R12 post-mortem: k_mlp alone cost ~100 us (2 blocks/CU from 72 KB LDS, two
// 64 KB weight stagings + 4 full-drain barriers, 2 serialized block rounds),
// while the store stream needs only ~85 us. The staging was the bottleneck.
//
// Fix: each thread reads its own weight row W[r][0..127] (512 B) directly
// from global as 32 x float4 (L2-resident: W1+W2 = 128 KB total; g=0/g=1
// duplicates hit L1). Kills both stagings, 2 barriers, and 64 KB of LDS.
// LDS 72 KB -> 8 KB; __launch_bounds__(256,4) => all 1024 blocks co-resident
// (4/CU, 16 waves/CU): every block's compute hides under the device-wide
// store stream.
//
// Numerics: weight values + FMA order (k4 0..31, x/y/z/w), embed, SiLU and
// the store tail are identical to R11 (the XOR swizzle only permuted LDS
// slots, not summation order) -> bitwise-same output, absmax unchanged.
//
//   thread tile: 1 neuron (r = tid&127) x 4 batches (g = tid>>7);
//   LDS: EH[8][128] (emb, later h2) + H1[8][128] = 8 KB.
//   store tail: proven pattern, out[b,0,i,j] = h2[b,j].
// ---------------------------------------------------------------------------
__global__ __launch_bounds__(256, 4) void k_fused(
    const float* __restrict__ t,
    const float* __restrict__ W1, const float* __restrict__ b1,
    const float* __restrict__ W2, const float* __restrict__ b2,
    float* __restrict__ out)
{
    __shared__ __attribute__((aligned(16))) float EH[8 * 128]; // emb -> h2
    __shared__ __attribute__((aligned(16))) float H1[8 * 128];

    const int tid  = threadIdx.x;
    const int base = blockIdx.x * 8;

    const int r = tid & 127;   // neuron
    const int g = tid >> 7;    // wave-uniform: batches 4g..4g+3

    // ---- embedding: 8 batches x 64 freqs = 512 items, 2/thread ----
    #pragma unroll
    for (int i = 0; i < 2; ++i) {
        int idx = i * 256 + tid;
        int b = idx >> 6, k = idx & 63;
        double a   = (double)k * (6.907755278982137 / 63.0);
        float freq = (float)exp(a);
        float ang  = 6.2831853071795865f * freq;
        float ph   = t[base + b] * ang;
        float sv, cv;
        sincosf(ph, &sv, &cv);
        EH[b * 128 + k]      = sv;
        EH[b * 128 + 64 + k] = cv;
    }
    __syncthreads();

    // ---- layer 1: H1[b][r] = silu(b1[r] + sum_k emb[b][k]*W1[r,k]) ----
    {
        const f32x4* wp = (const f32x4*)(W1 + r * 128);  // this thread's row
        float acc[4];
        float bv = b1[r];
        #pragma unroll
        for (int m = 0; m < 4; ++m) acc[m] = bv;
        #pragma unroll 4
        for (int k4 = 0; k4 < 32; ++k4) {
            f32x4 w = wp[k4];
            #pragma unroll
            for (int m = 0; m < 4; ++m) {
                f32x4 ev = ((const f32x4*)(EH + (g * 4 + m) * 128))[k4]; // broadcast
                acc[m] = fmaf(w.x, ev.x, acc[m]);
                acc[m] = fmaf(w.y, ev.y, acc[m]);
                acc[m] = fmaf(w.z, ev.z, acc[m]);
                acc[m] = fmaf(w.w, ev.w, acc[m]);
            }
        }
        #pragma unroll
        for (int m = 0; m < 4; ++m) {
            float a = acc[m];
            H1[(g * 4 + m) * 128 + r] = a / (1.0f + expf(-a));   // SiLU
        }
    }
    __syncthreads();

    // ---- layer 2: EH[b][r] = silu(b2[r] + sum_k H1[b][k]*W2[r,k]) ----
    {
        const f32x4* wp = (const f32x4*)(W2 + r * 128);
        float acc[4];
        float bv = b2[r];
        #pragma unroll
        for (int m = 0; m < 4; ++m) acc[m] = bv;
        #pragma unroll 4
        for (int k4 = 0; k4 < 32; ++k4) {
            f32x4 w = wp[k4];
            #pragma unroll
            for (int m = 0; m < 4; ++m) {
                f32x4 ev = ((const f32x4*)(H1 + (g * 4 + m) * 128))[k4]; // broadcast
                acc[m] = fmaf(w.x, ev.x, acc[m]);
                acc[m] = fmaf(w.y, ev.y, acc[m]);
                acc[m] = fmaf(w.z, ev.z, acc[m]);
                acc[m] = fmaf(w.w, ev.w, acc[m]);
            }
        }
        #pragma unroll
        for (int m = 0; m < 4; ++m) {
            float a = acc[m];
            EH[(g * 4 + m) * 128 + r] = a / (1.0f + expf(-a));   // SiLU
        }
    }
    __syncthreads();

    // ---- broadcast store (proven pattern): image = 4096 float4; thread
    // writes chunks c*256+tid; in-row column (tid&31) invariant -> v loaded
    // once per image.
    #pragma unroll
    for (int m = 0; m < 8; ++m) {
        f32x4 v = *(const f32x4*)&EH[m * 128 + (tid & 31) * 4];
        f32x4* d = (f32x4*)(out + (size_t)(base + m) * 16384);
        #pragma unroll
        for (int c = 0; c < 16; ++c) {
            d[c * 256 + tid] = v;
        }
    }
}

extern "C" void kernel_launch(void* const* d_in, const int* in_sizes, int n_in,
                              void* d_out, int out_size, void* d_ws, size_t ws_size,
                              hipStream_t stream) {
    const float* t  = (const float*)d_in[0];
    const float* W1 = (const float*)d_in[1];
    const float* b1 = (const float*)d_in[2];
    const float* W2 = (const float*)d_in[3];
    const float* b2 = (const float*)d_in[4];
    float* out = (float*)d_out;
    const int B = in_sizes[0];   // 8192

    k_fused<<<B / 8, 256, 0, stream>>>(t, W1, b1, W2, b2, out);
}